// Round 6
// baseline (45321.335 us; speedup 1.0000x reference)
//
#include <hip/hip_runtime.h>
#include <hip/hip_bf16.h>
#include <stdint.h>

#define SEQ   512
#define BATCH 128
#define DIM   1024
#define BD    (BATCH * DIM)   // 131072
#define WELEM (4 * DIM * DIM) // elements per weight matrix
#define KT    128             // K-tile
#define LDT   136             // padded tile leading dim (elements, +8 pad)

typedef __bf16 bf16x8 __attribute__((ext_vector_type(8)));
typedef float  f32x4  __attribute__((ext_vector_type(4)));

__device__ __forceinline__ float sigf(float x) { return 1.0f / (1.0f + __expf(-x)); }

// Convert an f32 weight matrix to bf16 (once per launch).
__global__ __launch_bounds__(256) void cvt_w(
    const float* __restrict__ src, __hip_bfloat16* __restrict__ dst)
{
    int i = (blockIdx.x * blockDim.x + threadIdx.x) * 4;
    float4 v = *reinterpret_cast<const float4*>(src + i);
    dst[i + 0] = __float2bfloat16(v.x);
    dst[i + 1] = __float2bfloat16(v.y);
    dst[i + 2] = __float2bfloat16(v.z);
    dst[i + 3] = __float2bfloat16(v.w);
}

__global__ __launch_bounds__(256) void bias_sum(
    const float* __restrict__ bih, const float* __restrict__ bhh,
    float* __restrict__ bsum)
{
    int i = blockIdx.x * blockDim.x + threadIdx.x;   // over 4*DIM
    bsum[i] = bih[i] + bhh[i];
}

// One LSTM cell step. 256 blocks x 256 threads.
// Block bx: mh = bx&1 (M-half: batch rows mh*64..+64), ng = bx>>1 (j-pack of 8).
// N-cols (32): c = g*8+jj for gates g=0..3 (i,f,g,o), jj=0..7 -> cell-complete block.
// K = 2048: phase 0 = A1 @ Wih^T (k 0..1023), phase 1 = A2 @ Whh^T.
// K-loop: 16 double-buffered KT=128 LDS tiles; 4 waves K-split the tile (wave w
// takes k-window w*32); each wave: m_t=4 x n_t=2 MFMA tiles. Cross-wave partial
// reduction via LDS atomicAdd, then thread-per-cell epilogue (pad-mask semantics
// identical to the verified R4/R5 kernels).
__global__ __launch_bounds__(256) void lstm_cell2(
    const int* __restrict__ xrow,
    const float* __restrict__ embf,            // f32 embedding (gather==1)
    const __hip_bfloat16* __restrict__ a1b,    // bf16 A1 (gather==0: h1cell)
    const __hip_bfloat16* __restrict__ a2b,    // bf16 recurrent state
    const __hip_bfloat16* __restrict__ Wih,    // bf16 ws copy [4D, D]
    const __hip_bfloat16* __restrict__ Whh,    // bf16 ws copy
    const float* __restrict__ bsum,            // bih+bhh [4*DIM]
    const float* __restrict__ c_in,
    const float* __restrict__ fb_h,
    const float* __restrict__ fb_c,
    float* __restrict__ h_out,
    float* __restrict__ c_out,
    __hip_bfloat16* __restrict__ hbf_out,
    __hip_bfloat16* __restrict__ h1cell_out,   // non-null only for layer 1 (unmasked h)
    int gather)
{
    __shared__ __hip_bfloat16 Ab[2][64 * LDT];   // 34,816 B
    __shared__ __hip_bfloat16 Bb[2][32 * LDT];   // 17,408 B
    __shared__ float part[8 * 16 * 17];          //  8,704 B

    const int tid  = threadIdx.x;
    const int wv   = tid >> 6;
    const int lane = tid & 63;
    const int quad = lane >> 4;
    const int l16  = lane & 15;
    const int mh   = blockIdx.x & 1;
    const int ng   = blockIdx.x >> 1;
    const int j0   = ng * 8;

    for (int i = tid; i < 8 * 16 * 17; i += 256) part[i] = 0.0f;

    uint4 aR[4], bR[2];

    // ---- chunk loader (global -> regs), coalesced 16B per thread-slot ----
    #define LOAD_CHUNK(c)                                                        \
    {                                                                            \
        const int kb = (c) * KT;                                                 \
        const int phase = kb >> 10;                                              \
        const int ko = kb & 1023;                                                \
        _Pragma("unroll")                                                        \
        for (int i = 0; i < 4; ++i) {                                            \
            int s = i * 256 + tid;                                               \
            int row = s >> 4, c16 = s & 15;                                      \
            int gr = mh * 64 + row;                                              \
            int col = ko + c16 * 8;                                              \
            if (phase == 0) {                                                    \
                if (gather) {                                                    \
                    const float* p = embf + (size_t)xrow[gr] * DIM + col;        \
                    float4 x0 = *(const float4*)p;                               \
                    float4 x1 = *(const float4*)(p + 4);                         \
                    union { uint4 u; __bf16 h[8]; } t;                           \
                    t.h[0] = (__bf16)x0.x; t.h[1] = (__bf16)x0.y;                \
                    t.h[2] = (__bf16)x0.z; t.h[3] = (__bf16)x0.w;                \
                    t.h[4] = (__bf16)x1.x; t.h[5] = (__bf16)x1.y;                \
                    t.h[6] = (__bf16)x1.z; t.h[7] = (__bf16)x1.w;                \
                    aR[i] = t.u;                                                 \
                } else {                                                         \
                    aR[i] = *(const uint4*)(a1b + (size_t)gr * DIM + col);       \
                }                                                                \
            } else {                                                             \
                aR[i] = *(const uint4*)(a2b + (size_t)gr * DIM + col);           \
            }                                                                    \
        }                                                                        \
        const __hip_bfloat16* W = phase ? Whh : Wih;                             \
        _Pragma("unroll")                                                        \
        for (int i = 0; i < 2; ++i) {                                            \
            int s = i * 256 + tid;                                               \
            int row = s >> 4, c16 = s & 15;                                      \
            int g = row >> 3, jj = row & 7;                                      \
            bR[i] = *(const uint4*)(W + (size_t)(g * DIM + j0 + jj) * DIM        \
                                      + ko + c16 * 8);                           \
        }                                                                        \
    }

    #define WRITE_CHUNK(buf)                                                     \
    {                                                                            \
        _Pragma("unroll")                                                        \
        for (int i = 0; i < 4; ++i) {                                            \
            int s = i * 256 + tid;                                               \
            int row = s >> 4, c16 = s & 15;                                      \
            *(uint4*)&Ab[(buf)][row * LDT + c16 * 8] = aR[i];                    \
        }                                                                        \
        _Pragma("unroll")                                                        \
        for (int i = 0; i < 2; ++i) {                                            \
            int s = i * 256 + tid;                                               \
            int row = s >> 4, c16 = s & 15;                                      \
            *(uint4*)&Bb[(buf)][row * LDT + c16 * 8] = bR[i];                    \
        }                                                                        \
    }

    f32x4 acc[4][2];
    #pragma unroll
    for (int mt = 0; mt < 4; ++mt) { acc[mt][0] = (f32x4)(0.f); acc[mt][1] = (f32x4)(0.f); }

    const int base = wv * 32 + quad * 8;   // this wave's k-window within the tile

    LOAD_CHUNK(0);
    WRITE_CHUNK(0);
    __syncthreads();

    for (int c = 0; c < 16; ++c) {
        if (c < 15) LOAD_CHUNK(c + 1);     // in flight during compute
        {
            const __hip_bfloat16* A = Ab[c & 1];
            const __hip_bfloat16* B = Bb[c & 1];
            bf16x8 bfr[2];
            #pragma unroll
            for (int nt = 0; nt < 2; ++nt) {
                uint4 u = *(const uint4*)&B[(nt * 16 + l16) * LDT + base];
                bfr[nt] = __builtin_bit_cast(bf16x8, u);
            }
            #pragma unroll
            for (int mt = 0; mt < 4; ++mt) {
                uint4 ua = *(const uint4*)&A[(mt * 16 + l16) * LDT + base];
                bf16x8 af = __builtin_bit_cast(bf16x8, ua);
                acc[mt][0] = __builtin_amdgcn_mfma_f32_16x16x32_bf16(af, bfr[0], acc[mt][0], 0, 0, 0);
                acc[mt][1] = __builtin_amdgcn_mfma_f32_16x16x32_bf16(af, bfr[1], acc[mt][1], 0, 0, 0);
            }
        }
        __syncthreads();
        if (c < 15) {
            WRITE_CHUNK((c + 1) & 1);
            __syncthreads();
        }
    }

    // Cross-wave K-reduction. C/D layout (m89): col = lane&15, row = quad*4 + r.
    #pragma unroll
    for (int mt = 0; mt < 4; ++mt)
        #pragma unroll
        for (int nt = 0; nt < 2; ++nt)
            #pragma unroll
            for (int r = 0; r < 4; ++r)
                atomicAdd(&part[((mt * 2 + nt) * 16 + quad * 4 + r) * 17 + l16],
                          acc[mt][nt][r]);
    __syncthreads();

    // Epilogue: 512 cells (64 rows x 8 j), 2 per thread.
    #pragma unroll
    for (int half = 0; half < 2; ++half) {
        int cell = half * 256 + tid;
        int m = cell >> 3, jj = cell & 7;
        int mt = m >> 4, r = m & 15;
        float gate[4];
        #pragma unroll
        for (int g = 0; g < 4; ++g) {
            int ti  = mt * 2 + (g >> 1);
            int cit = (g & 1) * 8 + jj;
            gate[g] = part[(ti * 16 + r) * 17 + cit] + bsum[g * DIM + j0 + jj];
        }
        int brow = mh * 64 + m;
        size_t off = (size_t)brow * DIM + j0 + jj;
        float c_old = c_in[off];
        float cn = sigf(gate[1]) * c_old + sigf(gate[0]) * tanhf(gate[2]);
        float hn = sigf(gate[3]) * tanhf(cn);
        if (h1cell_out) h1cell_out[off] = __float2bfloat16(hn);  // unmasked, feeds layer 2
        bool pad = (xrow[brow] == 0);
        float hw = pad ? fb_h[off] : hn;
        float cw = pad ? fb_c[off] : cn;
        h_out[off]   = hw;
        c_out[off]   = cw;
        hbf_out[off] = __float2bfloat16(hw);
    }
    #undef LOAD_CHUNK
    #undef WRITE_CHUNK
}

__global__ __launch_bounds__(256) void init_state(
    const float* __restrict__ h0, const float* __restrict__ c0,
    const float* __restrict__ h02, const float* __restrict__ c02,
    float* __restrict__ h, float* __restrict__ c,
    float* __restrict__ h2, float* __restrict__ c2,
    __hip_bfloat16* __restrict__ hbf, __hip_bfloat16* __restrict__ h2bf)
{
    int i = blockIdx.x * blockDim.x + threadIdx.x;  // over B*D
    int j = i & (DIM - 1);
    float hv = h0[j], h2v = h02[j];
    h[i]  = hv;
    c[i]  = c0[j];
    h2[i] = h2v;
    c2[i] = c02[j];
    hbf[i]  = __float2bfloat16(hv);
    h2bf[i] = __float2bfloat16(h2v);
}

// Output buffer is FLOAT32 (reference's declared output dtype).
__global__ __launch_bounds__(256) void pack_out(
    const float* __restrict__ h, const float* __restrict__ c,
    const float* __restrict__ h2, const float* __restrict__ c2,
    float* __restrict__ out)
{
    int i = blockIdx.x * blockDim.x + threadIdx.x;  // over 4*B*D
    int sec = i >> 17;          // BD = 2^17
    int off = i & (BD - 1);
    const float* src = (sec == 0) ? h : (sec == 1) ? c : (sec == 2) ? h2 : c2;
    out[i] = src[off];
}

extern "C" void kernel_launch(void* const* d_in, const int* in_sizes, int n_in,
                              void* d_out, int out_size, void* d_ws, size_t ws_size,
                              hipStream_t stream) {
    (void)in_sizes; (void)n_in; (void)out_size; (void)ws_size;
    const int*   x    = (const int*)d_in[0];
    const float* emb  = (const float*)d_in[1];
    const float* Wih  = (const float*)d_in[2];
    const float* Whh  = (const float*)d_in[3];
    const float* bih  = (const float*)d_in[4];
    const float* bhh  = (const float*)d_in[5];
    const float* h0   = (const float*)d_in[6];
    const float* c0   = (const float*)d_in[7];
    const float* h02  = (const float*)d_in[8];
    const float* c02  = (const float*)d_in[9];

    // ws: 8 f32 state buffers + bsum + bf16 shadows + bf16 W copies (~22 MB).
    float* f = (float*)d_ws;
    float* hS[2]  = { f + 0 * BD, f + 1 * BD };
    float* cS[2]  = { f + 2 * BD, f + 3 * BD };
    float* h2S[2] = { f + 4 * BD, f + 5 * BD };
    float* c2S[2] = { f + 6 * BD, f + 7 * BD };
    float* bsum   = f + 8 * BD;                      // 4*DIM floats
    __hip_bfloat16* bfb = (__hip_bfloat16*)(bsum + 4 * DIM);
    __hip_bfloat16* hbf[2]  = { bfb + 0 * BD, bfb + 1 * BD };
    __hip_bfloat16* h2bf[2] = { bfb + 2 * BD, bfb + 3 * BD };
    __hip_bfloat16* h1cell  = bfb + 4 * BD;
    __hip_bfloat16* Wihb    = bfb + 5 * BD;
    __hip_bfloat16* Whhb    = Wihb + WELEM;

    cvt_w<<<WELEM / 1024, 256, 0, stream>>>(Wih, Wihb);
    cvt_w<<<WELEM / 1024, 256, 0, stream>>>(Whh, Whhb);
    bias_sum<<<(4 * DIM) / 256, 256, 0, stream>>>(bih, bhh, bsum);

    init_state<<<BD / 256, 256, 0, stream>>>(h0, c0, h02, c02,
        hS[0], cS[0], h2S[0], c2S[0], hbf[0], h2bf[0]);

    for (int t = 0; t < SEQ; ++t) {
        int in = t & 1, out = in ^ 1;
        const int* xrow = x + t * BATCH;
        // layer 1: A1 = emb[x[t]] (f32 gather), A2 = h_bf
        lstm_cell2<<<256, 256, 0, stream>>>(xrow, emb, nullptr, hbf[in],
            Wihb, Whhb, bsum,
            cS[in], hS[in], cS[in],
            hS[out], cS[out], hbf[out], h1cell, 1);
        // layer 2: A1 = h1 (unmasked bf16), A2 = h2_bf; pad fallback = layer-1 PRE-state
        lstm_cell2<<<256, 256, 0, stream>>>(xrow, emb, h1cell, h2bf[in],
            Wihb, Whhb, bsum,
            c2S[in], hS[in], cS[in],
            h2S[out], c2S[out], h2bf[out], nullptr, 0);
    }
    // SEQ even -> final states land in parity-0 buffers.
    pack_out<<<(4 * BD) / 256, 256, 0, stream>>>(hS[0], cS[0], h2S[0], c2S[0],
        (float*)d_out);
}